// Round 3
// baseline (38767.911 us; speedup 1.0000x reference)
//
#include <hip/hip_runtime.h>

// Problem sizes (fixed by reference)
#define TSTEPS 1024
#define BATCH  256
#define HID    512
#define OUTD   64

// Decomposition: 256 WGs x 256 thr, 1 WG/CU. 8 groups x 32 WGs.
// Group owns 32 batches; WG owns 16 hidden units (48 gate-rows of w_hh).
// Thread (b, ks): batch b in group, k-slice ks (64 of 512 h elements).
//
// R3: per-step launches (1024 kernels) instead of persistent+grid.sync.
// R1/R2 failed with identical absmax — can't distinguish silent cooperative-
// launch failure from a math bug. Kernel boundaries give device-wide sync +
// cross-XCD cache coherence for free; this isolates the math.
#define NWG    256
#define NTHR   256
#define UPW    16      // hidden units per WG
#define KPAD   68      // 64-float k-slice padded to 68 (16B-aligned)

__device__ __forceinline__ float red8(float v) {
  // sum across the 8 ks-lanes (lane ^ {1,2,4}); all 8 lanes end with the sum
  v += __shfl_xor(v, 1);
  v += __shfl_xor(v, 2);
  v += __shfl_xor(v, 4);
  return v;
}

__device__ __forceinline__ float sigmoidf_(float x) {
  float t = __expf(-fabsf(x));        // t in (0,1], no overflow
  float p = 1.f / (1.f + t);
  return x >= 0.f ? p : 1.f - p;
}

__device__ __forceinline__ float tanhf_(float x) {
  float t = __expf(-2.f * fabsf(x));  // t in (0,1], no overflow
  float p = (1.f - t) / (1.f + t);
  return x >= 0.f ? p : -p;
}

// One GRU time-step: reads h_s from hread, writes h_{s+1} to hwrite,
// and writes y_{s-1} (= hread @ w_out.T + b_out) to out[s-1] when s>0.
__global__ void __launch_bounds__(NTHR, 1)
gru_step(const float* __restrict__ target,
         const float* __restrict__ w_ih,
         const float* __restrict__ w_hh,
         const float* __restrict__ b_ih,
         const float* __restrict__ b_hh,
         const float* __restrict__ w_out,
         const float* __restrict__ b_out,
         const float* __restrict__ hread,   // [B,H] h_s
         float* __restrict__ hwrite,        // [B,H] h_{s+1}
         float* __restrict__ out,           // [T,B,O] (+ tail [B,H])
         int s)
{
  __shared__ float whh_s [3*UPW*8*KPAD];  // [48][8][KPAD] 104448 B
  __shared__ float wih_s [3*UPW*64];      // [48][64]       12288 B
  __shared__ float wout_s[2*8*KPAD];      // [2][8][KPAD]    4352 B
  __shared__ float bih_s [48];
  __shared__ float bhh_s [48];
  __shared__ float bout_s[2];

  const int bid = blockIdx.x;
  const int g   = bid >> 5;              // group 0..7
  const int cu  = bid & 31;              // wg within group
  const int tid = threadIdx.x;
  const int ln  = tid & 63;
  const int bl  = ((tid >> 6) << 3) | (ln >> 3); // batch-local 0..31
  const int bg  = (g << 5) | bl;                 // global batch
  const int ks  = ln & 7;                        // k-slice 0..7

  // ---- stage weights ----
  for (int i = tid; i < 48*HID; i += NTHR) {
    int c = i >> 9, k = i & 511;
    int grow = (c >> 4)*HID + cu*UPW + (c & 15);   // gate*512 + unit
    whh_s[(c*8 + (k >> 6))*KPAD + (k & 63)] = w_hh[grow*HID + k];
  }
  for (int i = tid; i < 48*64; i += NTHR) {
    int c = i >> 6, k = i & 63;
    int grow = (c >> 4)*HID + cu*UPW + (c & 15);
    wih_s[i] = w_ih[grow*OUTD + k];
  }
  for (int i = tid; i < 2*HID; i += NTHR) {
    int o2 = i >> 9, k = i & 511;
    wout_s[(o2*8 + (k >> 6))*KPAD + (k & 63)] = w_out[(cu*2 + o2)*HID + k];
  }
  if (tid < 48) {
    int grow = (tid >> 4)*HID + cu*UPW + (tid & 15);
    bih_s[tid] = b_ih[grow];
    bhh_s[tid] = b_hh[grow];
  }
  if (tid < 2) bout_s[tid] = b_out[cu*2 + tid];
  __syncthreads();

  // ---- load h_s slice (64 regs) + own-unit values ----
  const float* hsrc = hread + (size_t)bg*HID;
  float hreg[64];
  #pragma unroll
  for (int j = 0; j < 64; j += 4) {
    float4 v = *reinterpret_cast<const float4*>(hsrc + ks*64 + j);
    hreg[j+0]=v.x; hreg[j+1]=v.y; hreg[j+2]=v.z; hreg[j+3]=v.w;
  }
  float hown[UPW];
  #pragma unroll
  for (int j = 0; j < UPW; j += 4) {
    float4 v = *reinterpret_cast<const float4*>(hsrc + cu*UPW + j);
    hown[j+0]=v.x; hown[j+1]=v.y; hown[j+2]=v.z; hown[j+3]=v.w;
  }
  // ---- x_s slice (teacher forcing: x_0 = 0, x_s = target[s-1]) ----
  float xreg[8];
  if (s > 0) {
    const float* xp = target + ((size_t)(s-1)*BATCH + bg)*OUTD + ks*8;
    float4 a = *reinterpret_cast<const float4*>(xp);
    float4 b = *reinterpret_cast<const float4*>(xp + 4);
    xreg[0]=a.x; xreg[1]=a.y; xreg[2]=a.z; xreg[3]=a.w;
    xreg[4]=b.x; xreg[5]=b.y; xreg[6]=b.z; xreg[7]=b.w;
  } else {
    #pragma unroll
    for (int j = 0; j < 8; ++j) xreg[j] = 0.f;
  }

  // ---- y_{s-1} = h_s @ w_out.T + b_out (this CU's 2 output cols) ----
  if (s > 0) {
    #pragma unroll
    for (int o2 = 0; o2 < 2; ++o2) {
      const float* row = wout_s + (o2*8 + ks)*KPAD;
      float acc = 0.f;
      #pragma unroll
      for (int j = 0; j < 64; ++j) acc = fmaf(hreg[j], row[j], acc);
      acc = red8(acc);
      if (ks == 0)
        out[((size_t)(s-1)*BATCH + bg)*OUTD + (cu*2 + o2)] = acc + bout_s[o2];
    }
  }

  // ---- gates for this WG's 16 units ----
  float hnew[UPW];
  #pragma unroll
  for (int u = 0; u < UPW; ++u) {
    const float* rr = whh_s + ((0*UPW + u)*8 + ks)*KPAD;
    const float* rz = whh_s + ((1*UPW + u)*8 + ks)*KPAD;
    const float* rn = whh_s + ((2*UPW + u)*8 + ks)*KPAD;
    float ghr = 0.f, ghz = 0.f, ghn = 0.f;
    #pragma unroll
    for (int j = 0; j < 64; ++j) {
      ghr = fmaf(hreg[j], rr[j], ghr);
      ghz = fmaf(hreg[j], rz[j], ghz);
      ghn = fmaf(hreg[j], rn[j], ghn);
    }
    const float* ir_ = wih_s + (0*UPW + u)*64 + ks*8;
    const float* iz_ = wih_s + (1*UPW + u)*64 + ks*8;
    const float* in_ = wih_s + (2*UPW + u)*64 + ks*8;
    float gir = 0.f, giz = 0.f, gin = 0.f;
    #pragma unroll
    for (int j = 0; j < 8; ++j) {
      gir = fmaf(xreg[j], ir_[j], gir);
      giz = fmaf(xreg[j], iz_[j], giz);
      gin = fmaf(xreg[j], in_[j], gin);
    }
    // r,z: gi+gh fused before reduce; n: i_n and h_n reduced separately
    float sr  = red8(ghr + gir);
    float sz  = red8(ghz + giz);
    float sni = red8(gin);
    float snh = red8(ghn);
    float r = sigmoidf_(sr + bih_s[u]      + bhh_s[u]);
    float z = sigmoidf_(sz + bih_s[16 + u] + bhh_s[16 + u]);
    float n = tanhf_((sni + bih_s[32 + u]) + r*(snh + bhh_s[32 + u]));
    hnew[u] = (1.f - z)*n + z*hown[u];
  }

  // ---- publish h_{s+1} (one lane per batch writes this WG's 16 units) ----
  float* hdst = hwrite + (size_t)bg*HID + cu*UPW;
  if (ks == 0) {
    #pragma unroll
    for (int j = 0; j < UPW; j += 4)
      *reinterpret_cast<float4*>(hdst + j) =
          make_float4(hnew[j], hnew[j+1], hnew[j+2], hnew[j+3]);
  }
}

// Tail: y_{T-1} = h_T @ w_out.T + b_out.
__global__ void __launch_bounds__(NTHR, 1)
gru_tail(const float* __restrict__ w_out,
         const float* __restrict__ b_out,
         const float* __restrict__ hlast,   // [B,H] h_T
         float* __restrict__ out)
{
  __shared__ float wout_s[2*8*KPAD];
  __shared__ float bout_s[2];

  const int bid = blockIdx.x;
  const int g   = bid >> 5;
  const int cu  = bid & 31;
  const int tid = threadIdx.x;
  const int ln  = tid & 63;
  const int bl  = ((tid >> 6) << 3) | (ln >> 3);
  const int bg  = (g << 5) | bl;
  const int ks  = ln & 7;

  for (int i = tid; i < 2*HID; i += NTHR) {
    int o2 = i >> 9, k = i & 511;
    wout_s[(o2*8 + (k >> 6))*KPAD + (k & 63)] = w_out[(cu*2 + o2)*HID + k];
  }
  if (tid < 2) bout_s[tid] = b_out[cu*2 + tid];
  __syncthreads();

  const float* hsrc = hlast + (size_t)bg*HID;
  float hreg[64];
  #pragma unroll
  for (int j = 0; j < 64; j += 4) {
    float4 v = *reinterpret_cast<const float4*>(hsrc + ks*64 + j);
    hreg[j+0]=v.x; hreg[j+1]=v.y; hreg[j+2]=v.z; hreg[j+3]=v.w;
  }
  #pragma unroll
  for (int o2 = 0; o2 < 2; ++o2) {
    const float* row = wout_s + (o2*8 + ks)*KPAD;
    float acc = 0.f;
    #pragma unroll
    for (int j = 0; j < 64; ++j) acc = fmaf(hreg[j], row[j], acc);
    acc = red8(acc);
    if (ks == 0)
      out[((size_t)(TSTEPS-1)*BATCH + bg)*OUTD + (cu*2 + o2)] = acc + bout_s[o2];
  }
}

extern "C" void kernel_launch(void* const* d_in, const int* in_sizes, int n_in,
                              void* d_out, int out_size, void* d_ws, size_t ws_size,
                              hipStream_t stream) {
  const float* code_vec = (const float*)d_in[0];
  const float* target   = (const float*)d_in[1];
  const float* w_ih     = (const float*)d_in[2];
  const float* w_hh     = (const float*)d_in[3];
  const float* b_ih     = (const float*)d_in[4];
  const float* b_hh     = (const float*)d_in[5];
  const float* w_out    = (const float*)d_in[6];
  const float* b_out    = (const float*)d_in[7];
  float* out = (float*)d_out;
  float* h0  = (float*)d_ws;                 // ping
  float* h1  = h0 + (size_t)BATCH*HID;       // pong

  for (int s = 0; s < TSTEPS; ++s) {
    const float* hread = (s == 0) ? code_vec : ((s & 1) ? h0 : h1);
    float* hwrite      = (s & 1) ? h1 : h0;  // s=0 -> h0, s=1 -> h1, ...
    gru_step<<<NWG, NTHR, 0, stream>>>(target, w_ih, w_hh, b_ih, b_hh,
                                       w_out, b_out, hread, hwrite, out, s);
  }
  // h_T was written by s=1023 (odd) -> h1
  gru_tail<<<NWG, NTHR, 0, stream>>>(w_out, b_out, h1, out);
  hipMemcpyAsync(out + (size_t)TSTEPS*BATCH*OUTD, h1,
                 (size_t)BATCH*HID*sizeof(float),
                 hipMemcpyDeviceToDevice, stream);
}